// Round 5
// baseline (930.157 us; speedup 1.0000x reference)
//
#include <hip/hip_runtime.h>

#define N_NODES 100000
#define N_EDGES 3200000
#define D 256
#define CAP 64                      // padded-CSR row capacity (mean deg 32)
#define OVF_MAX 8192

#define NB1 98                      // coarse buckets (row >> 10)
#define RPB1 1024                   // rows per coarse bucket
#define CAPB1 34816                 // bucket capacity (mean 32653, +12 sigma)
#define CHUNK 6144                  // edges per binA block (48 KB LDS staging)
#define NBLK_A ((N_EDGES + CHUNK - 1) / CHUNK)   // 521

#define SLICES 8                    // 128-row slices per coarse bucket
#define RPS 128                     // rows per slice (LDS pad = 64 KB)

#define CAST_BLOCKS 6250            // 25.6M elems / (256 thr * 16)
#define GEMM_BLOCKS (N_NODES / 16)  // 6250

typedef __attribute__((ext_vector_type(8))) short bf16x8;
typedef __attribute__((ext_vector_type(4))) float f32x4;

// ---------------- small persistent scratch (always device globals) ----------
__device__ unsigned short g_wtp[(size_t)16 * 8 * 64 * 8];   // 128 KB packed W^T
__device__ int   g_b1cur[NB1];                              // coarse bucket fill
__device__ int   g_novf;
__device__ int   g_ovf_row[OVF_MAX];
__device__ int2  g_ovf_edge[OVF_MAX];

// ---------------- big scratch: d_ws if big enough, else these fallbacks -----
__device__ unsigned short g_xb_fb[(size_t)N_NODES * D];     // 51.2 MB
__device__ unsigned       g_y_fb[(size_t)N_NODES * (D / 2)];// 51.2 MB
__device__ int2           g_binned_fb[(size_t)NB1 * CAPB1]; // 27.3 MB

// fp32 -> bf16 round-to-nearest-even
__device__ __forceinline__ unsigned short f2bf(float f) {
    unsigned u = __float_as_uint(f);
    unsigned r = u + 0x7fffu + ((u >> 16) & 1u);
    return (unsigned short)(r >> 16);
}

// ---------------------------------- setup: pack W^T bf16 + zero bucket fill
// packed index p = ((nt*8 + s)*64 + lane)*8 + i :
//   n = nt*16 + (lane&15), k = s*32 + (lane>>4)*8 + i  -> source W[k][n]
__global__ void setup_kernel(const float* __restrict__ W) {
    const int tid = threadIdx.x;
    if (blockIdx.x < 64) {
        int pb = (blockIdx.x * 256 + tid) * 4;
        #pragma unroll
        for (int j = 0; j < 4; ++j) {
            int p    = pb + j;
            int i8   = p & 7;
            int lane = (p >> 3) & 63;
            int s    = (p >> 9) & 7;
            int nt   = p >> 12;
            int n = nt * 16 + (lane & 15);
            int k = s * 32 + (lane >> 4) * 8 + i8;
            g_wtp[p] = f2bf(W[(size_t)k * D + n]);
        }
    }
    if (blockIdx.x == 0) {
        if (tid < NB1) g_b1cur[tid] = 0;
        if (tid == 0) g_novf = 0;
    }
}

// ------- fused: binA (coarse bin, line-sized burst flushes) || cast x->bf16
// binA per block: stage CHUNK edges bucket-sorted in LDS, reserve global space
// with one atomic per (block,bucket), flush ~504 B contiguous runs. All HBM
// writes are line-sized. Cast: fp32 -> bf16 streaming (needed one kernel later).
__launch_bounds__(256)
__global__ void binA_cast_kernel(const float* __restrict__ x,
                                 const float* __restrict__ edge_val,
                                 const int* __restrict__ edge_row,
                                 const int* __restrict__ edge_col,
                                 int2* __restrict__ binned,
                                 unsigned short* __restrict__ xb) {
    __shared__ int2 rec[CHUNK];              // 48 KB
    __shared__ unsigned char bid[CHUNK];     // 6 KB
    __shared__ int cnt[NB1];
    __shared__ int pre[NB1 + 1];
    __shared__ int bas[NB1];
    const int tid = threadIdx.x;
    const int b = blockIdx.x;

    if (b < NBLK_A) {
        const int e0 = b * CHUNK;
        for (int k = tid; k < NB1; k += 256) cnt[k] = 0;
        __syncthreads();
        #pragma unroll
        for (int j = 0; j < CHUNK / 256; ++j) {
            int e = e0 + tid + j * 256;
            if (e < N_EDGES) atomicAdd(&cnt[edge_row[e] >> 10], 1);
        }
        __syncthreads();
        if (tid == 0) {                      // serial scan over 98 buckets
            int run = 0;
            for (int k = 0; k < NB1; ++k) { pre[k] = run; run += cnt[k]; }
            pre[NB1] = run;
        }
        __syncthreads();
        for (int k = tid; k < NB1; k += 256)
            bas[k] = cnt[k] ? atomicAdd(&g_b1cur[k], cnt[k]) : 0;
        __syncthreads();
        for (int k = tid; k < NB1; k += 256) cnt[k] = 0;   // reuse as offsets
        __syncthreads();
        #pragma unroll
        for (int j = 0; j < CHUNK / 256; ++j) {
            int e = e0 + tid + j * 256;
            if (e < N_EDGES) {
                int r = edge_row[e];
                int k = r >> 10;
                int o = atomicAdd(&cnt[k], 1);
                int pos = pre[k] + o;
                int2 pk;
                pk.x = edge_col[e] | ((r & 1023) << 17); // col:17b | row_local:10b
                pk.y = __float_as_int(edge_val[e]);
                rec[pos] = pk;
                bid[pos] = (unsigned char)k;
            }
        }
        __syncthreads();
        const int total = pre[NB1];
        for (int i = tid; i < total; i += 256) {
            int k = bid[i];
            int dest = bas[k] + (i - pre[k]);
            int2 pk = rec[i];
            if (dest < CAPB1) {
                binned[(size_t)k * CAPB1 + dest] = pk;
            } else {
                int o = atomicAdd(&g_novf, 1);
                if (o < OVF_MAX) {
                    g_ovf_row[o] = (k << 10) | (pk.x >> 17);
                    int2 ov; ov.x = pk.x & 0x1FFFF; ov.y = pk.y;
                    g_ovf_edge[o] = ov;
                }
            }
        }
    } else {
        // cast: lane-interleaved float4 loads -> fully coalesced
        const size_t blockBase = (size_t)(b - NBLK_A) * 4096;
        #pragma unroll
        for (int j = 0; j < 4; ++j) {
            size_t idx = blockBase + (size_t)(j * 256 + tid) * 4;
            float4 f = *(const float4*)&x[idx];
            unsigned short o[4];
            o[0] = f2bf(f.x); o[1] = f2bf(f.y);
            o[2] = f2bf(f.z); o[3] = f2bf(f.w);
            *(uint2*)&xb[idx] = *(const uint2*)o;
        }
    }
}

// ---------------- fused binB + SpMM: the fine scatter never leaves LDS
// Block (bkt, slice) streams the bucket's records, keeps its 128-row slice,
// scatters into a 64 KB LDS padded-CSR, then gathers Y = A*x for those rows.
// 256 threads = 2 groups x 128; group handles one row at a time (t = feature
// pair). LDS pad reads are wave-broadcast (same address across lanes).
__launch_bounds__(256)
__global__ void bin_spmm_kernel(const int2* __restrict__ binned,
                                const unsigned short* __restrict__ xbp,
                                unsigned* __restrict__ y) {
    __shared__ int2 pad[RPS * CAP];          // 64 KB
    __shared__ int cur[RPS];
    const int tid   = threadIdx.x;
    const int bkt   = blockIdx.x >> 3;
    const int slice = blockIdx.x & 7;

    const int n = min(g_b1cur[bkt], CAPB1);
    const int2* src = &binned[(size_t)bkt * CAPB1];

    if (tid < RPS) cur[tid] = 0;
    __syncthreads();
    // filter + LDS scatter (~1/8 of records match this slice)
    for (int i = tid; i < n; i += 256) {
        int2 pk = src[i];
        int rl = pk.x >> 17;                 // 10-bit row_local in bucket
        if ((rl >> 7) == slice) {
            int rl7 = rl & 127;
            int slot = atomicAdd(&cur[rl7], 1);
            int2 o2; o2.x = pk.x & 0x1FFFF; o2.y = pk.y;
            if (slot < CAP) {
                pad[(rl7 << 6) + slot] = o2;
            } else {
                int o = atomicAdd(&g_novf, 1);
                if (o < OVF_MAX) {
                    g_ovf_row[o] = (bkt << 10) + (slice << 7) + rl7;
                    g_ovf_edge[o] = o2;
                }
            }
        }
    }
    __syncthreads();

    const int grp = tid >> 7;                // 2 row groups
    const int t   = tid & 127;               // feature pair 2t, 2t+1
    const unsigned* xb = (const unsigned*)xbp;
    const int novf = min(g_novf, OVF_MAX);

    for (int rp = 0; rp < RPS / 2; ++rp) {
        const int rl7 = rp * 2 + grp;
        const int row = (bkt << 10) + (slice << 7) + rl7;
        if (row >= N_NODES) continue;
        const int deg = min(cur[rl7], CAP);
        const int2* prow = &pad[rl7 << 6];
        float a0 = 0.f, a1 = 0.f;
        int i = 0;
        for (; i + 3 < deg; i += 4) {
            int2 e0 = prow[i];
            int2 e1 = prow[i + 1];
            int2 e2 = prow[i + 2];
            int2 e3 = prow[i + 3];
            unsigned p0 = xb[(size_t)e0.x * (D / 2) + t];
            unsigned p1 = xb[(size_t)e1.x * (D / 2) + t];
            unsigned p2 = xb[(size_t)e2.x * (D / 2) + t];
            unsigned p3 = xb[(size_t)e3.x * (D / 2) + t];
            float v0 = __int_as_float(e0.y);
            float v1 = __int_as_float(e1.y);
            float v2 = __int_as_float(e2.y);
            float v3 = __int_as_float(e3.y);
            a0 += v0 * __uint_as_float(p0 << 16);
            a1 += v0 * __uint_as_float(p0 & 0xffff0000u);
            a0 += v1 * __uint_as_float(p1 << 16);
            a1 += v1 * __uint_as_float(p1 & 0xffff0000u);
            a0 += v2 * __uint_as_float(p2 << 16);
            a1 += v2 * __uint_as_float(p2 & 0xffff0000u);
            a0 += v3 * __uint_as_float(p3 << 16);
            a1 += v3 * __uint_as_float(p3 & 0xffff0000u);
        }
        for (; i < deg; ++i) {
            int2 e0 = prow[i];
            unsigned p0 = xb[(size_t)e0.x * (D / 2) + t];
            float v0 = __int_as_float(e0.y);
            a0 += v0 * __uint_as_float(p0 << 16);
            a1 += v0 * __uint_as_float(p0 & 0xffff0000u);
        }
        if (novf > 0) {                      // correctness fallback (empty)
            for (int j = 0; j < novf; ++j) {
                if (g_ovf_row[j] == row) {
                    int2 ee = g_ovf_edge[j];
                    float v0 = __int_as_float(ee.y);
                    unsigned p0 = xb[(size_t)ee.x * (D / 2) + t];
                    a0 += v0 * __uint_as_float(p0 << 16);
                    a1 += v0 * __uint_as_float(p0 & 0xffff0000u);
                }
            }
        }
        // no relu: out = relu(Y @ W) happens in the GEMM epilogue
        __builtin_nontemporal_store(
            (unsigned)f2bf(a0) | ((unsigned)f2bf(a1) << 16),
            &y[(size_t)row * (D / 2) + t]);
    }
}

// --------------------------- out = relu(Y @ W), per-wave 16x64 tile, K=256
__launch_bounds__(256)
__global__ void gemm_kernel(const unsigned short* __restrict__ Yb,
                            float* __restrict__ out) {
    __shared__ float tile[4][16][68];
    const int g    = blockIdx.x;
    const int wave = threadIdx.x >> 6;
    const int lane = threadIdx.x & 63;
    const int m0   = g * 16;
    const int n0   = wave * 64;
    const int lm   = lane & 15;
    const int q    = lane >> 4;

    f32x4 acc0 = {}, acc1 = {}, acc2 = {}, acc3 = {};

    #pragma unroll
    for (int s = 0; s < 8; ++s) {
        bf16x8 av = *(const bf16x8*)&Yb[(size_t)(m0 + lm) * D + s * 32 + q * 8];
        const unsigned short* bp =
            &g_wtp[((size_t)(wave * 4) * 8 + s) * 512 + lane * 8];
        bf16x8 b0 = *(const bf16x8*)&bp[0 * 4096];
        bf16x8 b1 = *(const bf16x8*)&bp[1 * 4096];
        bf16x8 b2 = *(const bf16x8*)&bp[2 * 4096];
        bf16x8 b3 = *(const bf16x8*)&bp[3 * 4096];
        acc0 = __builtin_amdgcn_mfma_f32_16x16x32_bf16(av, b0, acc0, 0, 0, 0);
        acc1 = __builtin_amdgcn_mfma_f32_16x16x32_bf16(av, b1, acc1, 0, 0, 0);
        acc2 = __builtin_amdgcn_mfma_f32_16x16x32_bf16(av, b2, acc2, 0, 0, 0);
        acc3 = __builtin_amdgcn_mfma_f32_16x16x32_bf16(av, b3, acc3, 0, 0, 0);
    }

    #pragma unroll
    for (int r = 0; r < 4; ++r) {
        tile[wave][q * 4 + r][ 0 + lm] = acc0[r];
        tile[wave][q * 4 + r][16 + lm] = acc1[r];
        tile[wave][q * 4 + r][32 + lm] = acc2[r];
        tile[wave][q * 4 + r][48 + lm] = acc3[r];
    }
    const int row  = lane >> 2;
    const int cseg = (lane & 3) * 16;
    float ov[16];
    #pragma unroll
    for (int j = 0; j < 16; ++j)
        ov[j] = fmaxf(tile[wave][row][cseg + j], 0.f);
    float* dst = &out[(size_t)(m0 + row) * D + n0 + cseg];
    #pragma unroll
    for (int j = 0; j < 4; ++j)
        __builtin_nontemporal_store(*(const f32x4*)&ov[j * 4], (f32x4*)&dst[j * 4]);
}

// ---------------------------------------------------------------- launcher
#define XB_BYTES   ((size_t)N_NODES * D * 2)            // 51.2 MB
#define Y_BYTES    ((size_t)N_NODES * D * 2)            // 51.2 MB
#define BIN_BYTES  ((size_t)NB1 * CAPB1 * 8)            // 27.3 MB
#define ALIGNUP(v) (((v) + 255) & ~(size_t)255)

extern "C" void kernel_launch(void* const* d_in, const int* in_sizes, int n_in,
                              void* d_out, int out_size, void* d_ws, size_t ws_size,
                              hipStream_t stream) {
    const float* x        = (const float*)d_in[0];
    const float* weight   = (const float*)d_in[1];
    const float* edge_val = (const float*)d_in[2];
    const int*   edge_row = (const int*)d_in[3];
    const int*   edge_col = (const int*)d_in[4];
    float* out = (float*)d_out;

    static void* s_xb = nullptr; static void* s_y = nullptr;
    static void* s_bin = nullptr;
    if (!s_xb) {
        hipGetSymbolAddress(&s_xb,  HIP_SYMBOL(g_xb_fb));
        hipGetSymbolAddress(&s_y,   HIP_SYMBOL(g_y_fb));
        hipGetSymbolAddress(&s_bin, HIP_SYMBOL(g_binned_fb));
    }
    unsigned short* xb;  unsigned* y;  int2* binned;
    const size_t need = ALIGNUP(XB_BYTES) + ALIGNUP(Y_BYTES) + ALIGNUP(BIN_BYTES);
    if (d_ws && ws_size >= need) {
        char* p = (char*)d_ws;
        xb     = (unsigned short*)p; p += ALIGNUP(XB_BYTES);
        y      = (unsigned*)p;       p += ALIGNUP(Y_BYTES);
        binned = (int2*)p;
    } else {
        xb     = (unsigned short*)s_xb;
        y      = (unsigned*)s_y;
        binned = (int2*)s_bin;
    }

    setup_kernel<<<64, 256, 0, stream>>>(weight);
    binA_cast_kernel<<<NBLK_A + CAST_BLOCKS, 256, 0, stream>>>(
        x, edge_val, edge_row, edge_col, binned, xb);
    bin_spmm_kernel<<<NB1 * SLICES, 256, 0, stream>>>(binned, xb, y);
    gemm_kernel<<<GEMM_BLOCKS, 256, 0, stream>>>((const unsigned short*)y, out);
}

// Round 6
// 620.103 us; speedup vs baseline: 1.5000x; 1.5000x over previous
//
#include <hip/hip_runtime.h>

#define N_NODES 100000
#define N_EDGES 3200000
#define D 256
#define OVF_MAX 8192

#define NB1 98                      // coarse buckets (row >> 10)
#define CAPB1 34816                 // bucket capacity (mean 32653, +12 sigma)
#define CHUNK 6144                  // edges per binA block (48 KB LDS staging)
#define NBLK_A ((N_EDGES + CHUNK - 1) / CHUNK)   // 521

#define NQ (NB1 * 4)                // binB blocks: (bucket, quarter) = 392
#define QROWS 256                   // rows per quarter
#define QCAP 9216                   // compact segment cap (mean 8192, +11 sigma)

#define CAST_BLOCKS 6250            // 25.6M elems / (256 thr * 16)
#define GEMM_BLOCKS (N_NODES / 16)  // 6250
#define SPMM_HALF 50000             // rows per spmm launch (visibility split)

typedef __attribute__((ext_vector_type(8))) short bf16x8;
typedef __attribute__((ext_vector_type(4))) float f32x4;

// ---------------- small persistent scratch (always device globals) ----------
__device__ unsigned short g_wtp[(size_t)16 * 8 * 64 * 8];   // 128 KB packed W^T
__device__ int   g_b1cur[NB1 * 16];                         // 64B-padded counters
__device__ int   g_novf;
__device__ int   g_ovf_row[OVF_MAX];
__device__ int2  g_ovf_edge[OVF_MAX];

// ---------------- big scratch: d_ws if big enough, else these fallbacks -----
__device__ unsigned short g_xb_fb[(size_t)N_NODES * D];     // 51.2 MB
__device__ unsigned       g_y_fb[(size_t)N_NODES * (D / 2)];// 51.2 MB
__device__ int2           g_binned_fb[(size_t)NB1 * CAPB1]; // 27.3 MB
__device__ int2           g_grp_fb[(size_t)NQ * QCAP];      // 28.9 MB compact recs
__device__ int2           g_rofs_fb[(size_t)NQ * QROWS];    // 803 KB {ofs,cnt}/row

// fp32 -> bf16 round-to-nearest-even
__device__ __forceinline__ unsigned short f2bf(float f) {
    unsigned u = __float_as_uint(f);
    unsigned r = u + 0x7fffu + ((u >> 16) & 1u);
    return (unsigned short)(r >> 16);
}

// ---------------------------------- setup: pack W^T bf16 + zero counters
__global__ void setup_kernel(const float* __restrict__ W) {
    const int tid = threadIdx.x;
    if (blockIdx.x < 64) {
        int pb = (blockIdx.x * 256 + tid) * 4;
        #pragma unroll
        for (int j = 0; j < 4; ++j) {
            int p    = pb + j;
            int i8   = p & 7;
            int lane = (p >> 3) & 63;
            int s    = (p >> 9) & 7;
            int nt   = p >> 12;
            int n = nt * 16 + (lane & 15);
            int k = s * 32 + (lane >> 4) * 8 + i8;
            g_wtp[p] = f2bf(W[(size_t)k * D + n]);
        }
    }
    if (blockIdx.x == 0) {
        for (int i = tid; i < NB1 * 16; i += 256) g_b1cur[i] = 0;
        if (tid == 0) g_novf = 0;
    }
}

// ---------------- binA: coarse bin by row>>10 with line-sized burst flushes
__launch_bounds__(256)
__global__ void binA_kernel(const float* __restrict__ edge_val,
                            const int* __restrict__ edge_row,
                            const int* __restrict__ edge_col,
                            int2* __restrict__ binned) {
    __shared__ int2 rec[CHUNK];              // 48 KB
    __shared__ unsigned char bid[CHUNK];     // 6 KB
    __shared__ int cnt[NB1];
    __shared__ int pre[NB1 + 1];
    __shared__ int bas[NB1];
    const int tid = threadIdx.x;
    const int e0 = blockIdx.x * CHUNK;

    for (int k = tid; k < NB1; k += 256) cnt[k] = 0;
    __syncthreads();
    #pragma unroll
    for (int j = 0; j < CHUNK / 256; ++j) {
        int e = e0 + tid + j * 256;
        if (e < N_EDGES) atomicAdd(&cnt[edge_row[e] >> 10], 1);
    }
    __syncthreads();
    if (tid == 0) {                          // serial scan over 98 buckets
        int run = 0;
        for (int k = 0; k < NB1; ++k) { pre[k] = run; run += cnt[k]; }
        pre[NB1] = run;
    }
    __syncthreads();
    for (int k = tid; k < NB1; k += 256)
        bas[k] = cnt[k] ? atomicAdd(&g_b1cur[k * 16], cnt[k]) : 0;
    __syncthreads();
    for (int k = tid; k < NB1; k += 256) cnt[k] = 0;   // reuse as offsets
    __syncthreads();
    #pragma unroll
    for (int j = 0; j < CHUNK / 256; ++j) {
        int e = e0 + tid + j * 256;
        if (e < N_EDGES) {
            int r = edge_row[e];
            int k = r >> 10;
            int o = atomicAdd(&cnt[k], 1);
            int pos = pre[k] + o;
            int2 pk;
            pk.x = edge_col[e] | ((r & 1023) << 17); // col:17b | row_local:10b
            pk.y = __float_as_int(edge_val[e]);
            rec[pos] = pk;
            bid[pos] = (unsigned char)k;
        }
    }
    __syncthreads();
    const int total = pre[NB1];
    for (int i = tid; i < total; i += 256) {
        int k = bid[i];
        int dest = bas[k] + (i - pre[k]);
        int2 pk = rec[i];
        if (dest < CAPB1) {
            binned[(size_t)k * CAPB1 + dest] = pk;
        } else {
            int o = atomicAdd(&g_novf, 1);
            if (o < OVF_MAX) {
                g_ovf_row[o] = (k << 10) | (pk.x >> 17);
                int2 ov; ov.x = pk.x & 0x1FFFF; ov.y = pk.y;
                g_ovf_edge[o] = ov;
            }
        }
    }
}

// ---------------- binB_sort: (bucket, quarter) -> row-compact segment
// Two coalesced passes over the bucket (count -> scan -> place) build the
// quarter's 256 rows compactly in LDS, then flush line-aligned bursts +
// per-row {ofs,cnt}. The fine scatter never touches global memory.
__launch_bounds__(512)
__global__ void binB_sort_kernel(const int2* __restrict__ binned,
                                 int2* __restrict__ grp,
                                 int2* __restrict__ rofs) {
    __shared__ int2 srec[QCAP];              // 73.7 KB
    __shared__ int cnt[QROWS];
    __shared__ int ofs[QROWS];
    __shared__ int cur[QROWS];
    const int tid = threadIdx.x;
    const int b   = blockIdx.x >> 2;         // bucket
    const int qtr = blockIdx.x & 3;          // quarter (256 rows)

    const int n = min(g_b1cur[b * 16], CAPB1);
    const int2* src = &binned[(size_t)b * CAPB1];

    if (tid < QROWS) { cnt[tid] = 0; cur[tid] = 0; }
    __syncthreads();
    // pass 1: count this quarter's rows
    for (int i = tid; i < n; i += 512) {
        int rl = src[i].x >> 17;
        if ((rl >> 8) == qtr) atomicAdd(&cnt[rl & 255], 1);
    }
    __syncthreads();
    if (tid < QROWS) {                       // brute-force exclusive scan
        int s = 0;
        for (int j = 0; j < tid; ++j) s += cnt[j];
        ofs[tid] = s;
    }
    __syncthreads();
    // pass 2: place compactly (L2-hot re-read)
    for (int i = tid; i < n; i += 512) {
        int2 pk = src[i];
        int rl = pk.x >> 17;
        if ((rl >> 8) == qtr) {
            int r8 = rl & 255;
            int p = ofs[r8] + atomicAdd(&cur[r8], 1);
            int2 o2; o2.x = pk.x & 0x1FFFF; o2.y = pk.y;
            if (p < QCAP) {
                srec[p] = o2;
            } else {
                int o = atomicAdd(&g_novf, 1);
                if (o < OVF_MAX) {
                    g_ovf_row[o] = (b << 10) + (qtr << 8) + r8;
                    g_ovf_edge[o] = o2;
                }
            }
        }
    }
    __syncthreads();
    // flush: contiguous, line-aligned (blk base = blk * 73728 B)
    const int total = min(ofs[QROWS - 1] + cnt[QROWS - 1], QCAP);
    int2* dst = &grp[(size_t)blockIdx.x * QCAP];
    for (int i = tid; i < total; i += 512) dst[i] = srec[i];
    if (tid < QROWS) {
        int s = min(ofs[tid], QCAP);
        int e = min(ofs[tid] + cnt[tid], QCAP);
        int2 oc; oc.x = s; oc.y = e - s;
        rofs[(size_t)blockIdx.x * QROWS + tid] = oc;
    }
}

// ---------------- cast: x fp32 -> bf16, standalone full-occupancy streaming
__launch_bounds__(256)
__global__ void cast_kernel(const float* __restrict__ x,
                            unsigned short* __restrict__ xb) {
    const size_t blockBase = (size_t)blockIdx.x * 4096;
    const int tid = threadIdx.x;
    #pragma unroll
    for (int j = 0; j < 4; ++j) {
        size_t idx = blockBase + (size_t)(j * 256 + tid) * 4;
        float4 f = *(const float4*)&x[idx];
        unsigned short o[4];
        o[0] = f2bf(f.x); o[1] = f2bf(f.y);
        o[2] = f2bf(f.z); o[3] = f2bf(f.w);
        *(uint2*)&xb[idx] = *(const uint2*)o;
    }
}

// ---------------------------------------------------------------- SpMM
// Y = A * x_bf16, bf16 out. One 128-thread block per row (R4-proven form);
// thread t owns features 2t, 2t+1. Launched twice (row halves) so the top-5
// profiler cutoff drops to ~106 us and exposes the next-largest kernel.
__launch_bounds__(128)
__global__ void spmm_kernel(const int2* __restrict__ grp,
                            const int2* __restrict__ rofs,
                            const unsigned short* __restrict__ xbp,
                            unsigned* __restrict__ y,
                            int rowBase) {
    const int r = rowBase + blockIdx.x;
    const int t = threadIdx.x;
    const int blk = r >> 8;                  // (bucket, quarter) segment id
    const int2 oc = rofs[(size_t)blk * QROWS + (r & 255)];
    const int deg = oc.y;
    const long long* rowp =
        (const long long*)&grp[(size_t)blk * QCAP + oc.x];
    const unsigned* xb = (const unsigned*)xbp;

    float a0 = 0.f, a1 = 0.f;
    int i = 0;
    for (; i + 3 < deg; i += 4) {
        long long q0 = __builtin_nontemporal_load(&rowp[i]);
        long long q1 = __builtin_nontemporal_load(&rowp[i + 1]);
        long long q2 = __builtin_nontemporal_load(&rowp[i + 2]);
        long long q3 = __builtin_nontemporal_load(&rowp[i + 3]);
        unsigned p0 = xb[(size_t)(int)q0 * (D / 2) + t];
        unsigned p1 = xb[(size_t)(int)q1 * (D / 2) + t];
        unsigned p2 = xb[(size_t)(int)q2 * (D / 2) + t];
        unsigned p3 = xb[(size_t)(int)q3 * (D / 2) + t];
        float v0 = __int_as_float((int)(q0 >> 32));
        float v1 = __int_as_float((int)(q1 >> 32));
        float v2 = __int_as_float((int)(q2 >> 32));
        float v3 = __int_as_float((int)(q3 >> 32));
        a0 += v0 * __uint_as_float(p0 << 16);
        a1 += v0 * __uint_as_float(p0 & 0xffff0000u);
        a0 += v1 * __uint_as_float(p1 << 16);
        a1 += v1 * __uint_as_float(p1 & 0xffff0000u);
        a0 += v2 * __uint_as_float(p2 << 16);
        a1 += v2 * __uint_as_float(p2 & 0xffff0000u);
        a0 += v3 * __uint_as_float(p3 << 16);
        a1 += v3 * __uint_as_float(p3 & 0xffff0000u);
    }
    for (; i < deg; ++i) {
        long long q0 = __builtin_nontemporal_load(&rowp[i]);
        float v0 = __int_as_float((int)(q0 >> 32));
        unsigned p0 = xb[(size_t)(int)q0 * (D / 2) + t];
        a0 += v0 * __uint_as_float(p0 << 16);
        a1 += v0 * __uint_as_float(p0 & 0xffff0000u);
    }
    const int novf = min(g_novf, OVF_MAX);
    if (novf > 0) {                          // correctness fallback (empty)
        for (int j = 0; j < novf; ++j) {
            if (g_ovf_row[j] == r) {
                int2 e0 = g_ovf_edge[j];
                float v0 = __int_as_float(e0.y);
                unsigned p0 = xb[(size_t)e0.x * (D / 2) + t];
                a0 += v0 * __uint_as_float(p0 << 16);
                a1 += v0 * __uint_as_float(p0 & 0xffff0000u);
            }
        }
    }
    // no relu: out = relu(Y @ W) happens in the GEMM epilogue
    y[(size_t)r * (D / 2) + t] =
        (unsigned)f2bf(a0) | ((unsigned)f2bf(a1) << 16);
}

// --------------------------- out = relu(Y @ W), per-wave 16x64 tile, K=256
__launch_bounds__(256)
__global__ void gemm_kernel(const unsigned short* __restrict__ Yb,
                            float* __restrict__ out) {
    __shared__ float tile[4][16][68];
    const int g    = blockIdx.x;
    const int wave = threadIdx.x >> 6;
    const int lane = threadIdx.x & 63;
    const int m0   = g * 16;
    const int n0   = wave * 64;
    const int lm   = lane & 15;
    const int q    = lane >> 4;

    f32x4 acc0 = {}, acc1 = {}, acc2 = {}, acc3 = {};

    #pragma unroll
    for (int s = 0; s < 8; ++s) {
        bf16x8 av = *(const bf16x8*)&Yb[(size_t)(m0 + lm) * D + s * 32 + q * 8];
        const unsigned short* bp =
            &g_wtp[((size_t)(wave * 4) * 8 + s) * 512 + lane * 8];
        bf16x8 b0 = *(const bf16x8*)&bp[0 * 4096];
        bf16x8 b1 = *(const bf16x8*)&bp[1 * 4096];
        bf16x8 b2 = *(const bf16x8*)&bp[2 * 4096];
        bf16x8 b3 = *(const bf16x8*)&bp[3 * 4096];
        acc0 = __builtin_amdgcn_mfma_f32_16x16x32_bf16(av, b0, acc0, 0, 0, 0);
        acc1 = __builtin_amdgcn_mfma_f32_16x16x32_bf16(av, b1, acc1, 0, 0, 0);
        acc2 = __builtin_amdgcn_mfma_f32_16x16x32_bf16(av, b2, acc2, 0, 0, 0);
        acc3 = __builtin_amdgcn_mfma_f32_16x16x32_bf16(av, b3, acc3, 0, 0, 0);
    }

    #pragma unroll
    for (int r = 0; r < 4; ++r) {
        tile[wave][q * 4 + r][ 0 + lm] = acc0[r];
        tile[wave][q * 4 + r][16 + lm] = acc1[r];
        tile[wave][q * 4 + r][32 + lm] = acc2[r];
        tile[wave][q * 4 + r][48 + lm] = acc3[r];
    }
    const int row  = lane >> 2;
    const int cseg = (lane & 3) * 16;
    float ov[16];
    #pragma unroll
    for (int j = 0; j < 16; ++j)
        ov[j] = fmaxf(tile[wave][row][cseg + j], 0.f);
    float* dst = &out[(size_t)(m0 + row) * D + n0 + cseg];
    #pragma unroll
    for (int j = 0; j < 4; ++j)
        __builtin_nontemporal_store(*(const f32x4*)&ov[j * 4], (f32x4*)&dst[j * 4]);
}

// ---------------------------------------------------------------- launcher
#define XB_BYTES   ((size_t)N_NODES * D * 2)            // 51.2 MB
#define Y_BYTES    ((size_t)N_NODES * D * 2)            // 51.2 MB
#define BIN_BYTES  ((size_t)NB1 * CAPB1 * 8)            // 27.3 MB
#define GRP_BYTES  ((size_t)NQ * QCAP * 8)              // 28.9 MB
#define ROFS_BYTES ((size_t)NQ * QROWS * 8)             // 803 KB
#define ALIGNUP(v) (((v) + 255) & ~(size_t)255)

extern "C" void kernel_launch(void* const* d_in, const int* in_sizes, int n_in,
                              void* d_out, int out_size, void* d_ws, size_t ws_size,
                              hipStream_t stream) {
    const float* x        = (const float*)d_in[0];
    const float* weight   = (const float*)d_in[1];
    const float* edge_val = (const float*)d_in[2];
    const int*   edge_row = (const int*)d_in[3];
    const int*   edge_col = (const int*)d_in[4];
    float* out = (float*)d_out;

    static void* s_xb = nullptr; static void* s_y = nullptr;
    static void* s_bin = nullptr; static void* s_grp = nullptr;
    static void* s_rofs = nullptr;
    if (!s_xb) {
        hipGetSymbolAddress(&s_xb,   HIP_SYMBOL(g_xb_fb));
        hipGetSymbolAddress(&s_y,    HIP_SYMBOL(g_y_fb));
        hipGetSymbolAddress(&s_bin,  HIP_SYMBOL(g_binned_fb));
        hipGetSymbolAddress(&s_grp,  HIP_SYMBOL(g_grp_fb));
        hipGetSymbolAddress(&s_rofs, HIP_SYMBOL(g_rofs_fb));
    }
    unsigned short* xb;  unsigned* y;  int2* binned;  int2* grp;  int2* rofs;
    const size_t need = ALIGNUP(XB_BYTES) + ALIGNUP(Y_BYTES) +
                        ALIGNUP(BIN_BYTES) + ALIGNUP(GRP_BYTES) +
                        ALIGNUP(ROFS_BYTES);
    if (d_ws && ws_size >= need) {
        char* p = (char*)d_ws;
        xb     = (unsigned short*)p; p += ALIGNUP(XB_BYTES);
        y      = (unsigned*)p;       p += ALIGNUP(Y_BYTES);
        binned = (int2*)p;           p += ALIGNUP(BIN_BYTES);
        grp    = (int2*)p;           p += ALIGNUP(GRP_BYTES);
        rofs   = (int2*)p;
    } else {
        xb     = (unsigned short*)s_xb;
        y      = (unsigned*)s_y;
        binned = (int2*)s_bin;
        grp    = (int2*)s_grp;
        rofs   = (int2*)s_rofs;
    }

    setup_kernel<<<64, 256, 0, stream>>>(weight);
    binA_kernel<<<NBLK_A, 256, 0, stream>>>(edge_val, edge_row, edge_col, binned);
    binB_sort_kernel<<<NQ, 512, 0, stream>>>(binned, grp, rofs);
    cast_kernel<<<CAST_BLOCKS, 256, 0, stream>>>(x, xb);
    spmm_kernel<<<SPMM_HALF, 128, 0, stream>>>(grp, rofs, xb, y, 0);
    spmm_kernel<<<SPMM_HALF, 128, 0, stream>>>(grp, rofs, xb, y, SPMM_HALF);
    gemm_kernel<<<GEMM_BLOCKS, 256, 0, stream>>>((const unsigned short*)y, out);
}

// Round 7
// 613.660 us; speedup vs baseline: 1.5158x; 1.0105x over previous
//
#include <hip/hip_runtime.h>

#define N_NODES 100000
#define N_EDGES 3200000
#define D 256
#define OVF_MAX 8192

#define NB1 98                      // coarse buckets (row >> 10)
#define CAPB1 34816                 // bucket capacity (mean 32653, +12 sigma)
#define CHUNK 6144                  // edges per binA block (48 KB LDS staging)
#define NBLK_A ((N_EDGES + CHUNK - 1) / CHUNK)   // 521

#define NQ (NB1 * 4)                // binB blocks: (bucket, quarter) = 392
#define QROWS 256                   // rows per quarter
#define QCAP 9216                   // compact segment cap (mean 8192, +11 sigma)

#define CAST_BLOCKS 6250            // 25.6M elems / (256 thr * 16)
#define PACK_BLOCKS 64
#define GEMM_BLOCKS (N_NODES / 16)  // 6250
#define SPMM_QTR 25000              // rows per spmm launch (visibility split x4)

typedef __attribute__((ext_vector_type(8))) short bf16x8;
typedef __attribute__((ext_vector_type(4))) float f32x4;

// ---------------- small persistent scratch (always device globals) ----------
__device__ unsigned short g_wtp[(size_t)16 * 8 * 64 * 8];   // 128 KB packed W^T
__device__ int   g_b1cur[NB1 * 16];                         // 64B-padded counters
__device__ int   g_novf;
__device__ int   g_ovf_row[OVF_MAX];
__device__ int2  g_ovf_edge[OVF_MAX];

// ---------------- big scratch: d_ws if big enough, else these fallbacks -----
__device__ unsigned short g_xb_fb[(size_t)N_NODES * D];     // 51.2 MB
__device__ unsigned       g_y_fb[(size_t)N_NODES * (D / 2)];// 51.2 MB
__device__ int2           g_binned_fb[(size_t)NB1 * CAPB1]; // 27.3 MB
__device__ int2           g_grp_fb[(size_t)NQ * QCAP];      // 28.9 MB compact recs
__device__ int2           g_rofs_fb[(size_t)NQ * QROWS];    // 803 KB {ofs,cnt}/row

// fp32 -> bf16 round-to-nearest-even
__device__ __forceinline__ unsigned short f2bf(float f) {
    unsigned u = __float_as_uint(f);
    unsigned r = u + 0x7fffu + ((u >> 16) & 1u);
    return (unsigned short)(r >> 16);
}

// ------- fused K1: binA (coarse bin, burst flush) || cast x->bf16 || pack W
__launch_bounds__(256)
__global__ void binA_cast_pack_kernel(const float* __restrict__ x,
                                      const float* __restrict__ W,
                                      const float* __restrict__ edge_val,
                                      const int* __restrict__ edge_row,
                                      const int* __restrict__ edge_col,
                                      int2* __restrict__ binned,
                                      unsigned short* __restrict__ xb) {
    __shared__ int2 rec[CHUNK];              // 48 KB
    __shared__ unsigned char bid[CHUNK];     // 6 KB
    __shared__ int cnt[NB1];
    __shared__ int pre[NB1 + 1];
    __shared__ int bas[NB1];
    const int tid = threadIdx.x;
    const int b = blockIdx.x;

    if (b < NBLK_A) {
        // -------- binA: bin by row>>10, bucket-sorted LDS staging + bursts
        const int e0 = b * CHUNK;
        for (int k = tid; k < NB1; k += 256) cnt[k] = 0;
        __syncthreads();
        #pragma unroll
        for (int j = 0; j < CHUNK / 256; ++j) {
            int e = e0 + tid + j * 256;
            if (e < N_EDGES) atomicAdd(&cnt[edge_row[e] >> 10], 1);
        }
        __syncthreads();
        if (tid == 0) {                      // serial scan over 98 buckets
            int run = 0;
            for (int k = 0; k < NB1; ++k) { pre[k] = run; run += cnt[k]; }
            pre[NB1] = run;
        }
        __syncthreads();
        for (int k = tid; k < NB1; k += 256)
            bas[k] = cnt[k] ? atomicAdd(&g_b1cur[k * 16], cnt[k]) : 0;
        __syncthreads();
        for (int k = tid; k < NB1; k += 256) cnt[k] = 0;   // reuse as offsets
        __syncthreads();
        #pragma unroll
        for (int j = 0; j < CHUNK / 256; ++j) {
            int e = e0 + tid + j * 256;
            if (e < N_EDGES) {
                int r = edge_row[e];
                int k = r >> 10;
                int o = atomicAdd(&cnt[k], 1);
                int pos = pre[k] + o;
                int2 pk;
                pk.x = edge_col[e] | ((r & 1023) << 17); // col:17b | row_local:10b
                pk.y = __float_as_int(edge_val[e]);
                rec[pos] = pk;
                bid[pos] = (unsigned char)k;
            }
        }
        __syncthreads();
        const int total = pre[NB1];
        for (int i = tid; i < total; i += 256) {
            int k = bid[i];
            int dest = bas[k] + (i - pre[k]);
            int2 pk = rec[i];
            if (dest < CAPB1) {
                binned[(size_t)k * CAPB1 + dest] = pk;
            } else {
                int o = atomicAdd(&g_novf, 1);
                if (o < OVF_MAX) {
                    g_ovf_row[o] = (k << 10) | (pk.x >> 17);
                    int2 ov; ov.x = pk.x & 0x1FFFF; ov.y = pk.y;
                    g_ovf_edge[o] = ov;
                }
            }
        }
    } else if (b < NBLK_A + CAST_BLOCKS) {
        // -------- cast: lane-interleaved float4 loads -> fully coalesced
        const size_t blockBase = (size_t)(b - NBLK_A) * 4096;
        #pragma unroll
        for (int j = 0; j < 4; ++j) {
            size_t idx = blockBase + (size_t)(j * 256 + tid) * 4;
            float4 f = *(const float4*)&x[idx];
            unsigned short o[4];
            o[0] = f2bf(f.x); o[1] = f2bf(f.y);
            o[2] = f2bf(f.z); o[3] = f2bf(f.w);
            *(uint2*)&xb[idx] = *(const uint2*)o;
        }
    } else {
        // -------- pack W^T MFMA-fragment-contiguous:
        // p = ((nt*8+s)*64+lane)*8+i : n = nt*16+(lane&15),
        // k = s*32+(lane>>4)*8+i  -> source W[k][n]
        int pb = ((b - NBLK_A - CAST_BLOCKS) * 256 + tid) * 4;
        #pragma unroll
        for (int j = 0; j < 4; ++j) {
            int p    = pb + j;
            int i8   = p & 7;
            int lane = (p >> 3) & 63;
            int s    = (p >> 9) & 7;
            int nt   = p >> 12;
            int n = nt * 16 + (lane & 15);
            int k = s * 32 + (lane >> 4) * 8 + i8;
            g_wtp[p] = f2bf(W[(size_t)k * D + n]);
        }
    }
}

// ---------------- binB_sort: (bucket, quarter) -> row-compact segment
// Two coalesced passes over the bucket (count -> scan -> place) build the
// quarter's 256 rows compactly in LDS, then flush line-aligned bursts +
// per-row {ofs,cnt}. The fine scatter never touches global memory.
__launch_bounds__(512)
__global__ void binB_sort_kernel(const int2* __restrict__ binned,
                                 int2* __restrict__ grp,
                                 int2* __restrict__ rofs) {
    __shared__ int2 srec[QCAP];              // 73.7 KB
    __shared__ int cnt[QROWS];
    __shared__ int ofs[QROWS];
    __shared__ int cur[QROWS];
    const int tid = threadIdx.x;
    const int b   = blockIdx.x >> 2;         // bucket
    const int qtr = blockIdx.x & 3;          // quarter (256 rows)

    const int n = min(g_b1cur[b * 16], CAPB1);
    const int2* src = &binned[(size_t)b * CAPB1];

    if (tid < QROWS) { cnt[tid] = 0; cur[tid] = 0; }
    __syncthreads();
    // pass 1: count this quarter's rows
    for (int i = tid; i < n; i += 512) {
        int rl = src[i].x >> 17;
        if ((rl >> 8) == qtr) atomicAdd(&cnt[rl & 255], 1);
    }
    __syncthreads();
    if (tid < QROWS) {                       // brute-force exclusive scan
        int s = 0;
        for (int j = 0; j < tid; ++j) s += cnt[j];
        ofs[tid] = s;
    }
    __syncthreads();
    // pass 2: place compactly (L2-hot re-read)
    for (int i = tid; i < n; i += 512) {
        int2 pk = src[i];
        int rl = pk.x >> 17;
        if ((rl >> 8) == qtr) {
            int r8 = rl & 255;
            int p = ofs[r8] + atomicAdd(&cur[r8], 1);
            int2 o2; o2.x = pk.x & 0x1FFFF; o2.y = pk.y;
            if (p < QCAP) {
                srec[p] = o2;
            } else {
                int o = atomicAdd(&g_novf, 1);
                if (o < OVF_MAX) {
                    g_ovf_row[o] = (b << 10) + (qtr << 8) + r8;
                    g_ovf_edge[o] = o2;
                }
            }
        }
    }
    __syncthreads();
    // flush: contiguous, line-aligned (blk base = blk * 73728 B)
    const int total = min(ofs[QROWS - 1] + cnt[QROWS - 1], QCAP);
    int2* dst = &grp[(size_t)blockIdx.x * QCAP];
    for (int i = tid; i < total; i += 512) dst[i] = srec[i];
    if (tid < QROWS) {
        int s = min(ofs[tid], QCAP);
        int e = min(ofs[tid] + cnt[tid], QCAP);
        int2 oc; oc.x = s; oc.y = e - s;
        rofs[(size_t)blockIdx.x * QROWS + tid] = oc;
    }
}

// ---------------------------------------------------------------- SpMM
// Y = A * x_bf16, bf16 out. One 128-thread block per row; thread t owns
// features 2t, 2t+1. Launched 4x (row quarters) so the profiler's top-5
// cutoff drops to ~55 us: the largest non-spmm kernel MUST surface.
__launch_bounds__(128)
__global__ void spmm_kernel(const int2* __restrict__ grp,
                            const int2* __restrict__ rofs,
                            const unsigned short* __restrict__ xbp,
                            unsigned* __restrict__ y,
                            int rowBase) {
    const int r = rowBase + blockIdx.x;
    const int t = threadIdx.x;
    const int blk = r >> 8;                  // (bucket, quarter) segment id
    const int2 oc = rofs[(size_t)blk * QROWS + (r & 255)];
    const int deg = oc.y;
    const long long* rowp =
        (const long long*)&grp[(size_t)blk * QCAP + oc.x];
    const unsigned* xb = (const unsigned*)xbp;

    float a0 = 0.f, a1 = 0.f;
    int i = 0;
    for (; i + 3 < deg; i += 4) {
        long long q0 = __builtin_nontemporal_load(&rowp[i]);
        long long q1 = __builtin_nontemporal_load(&rowp[i + 1]);
        long long q2 = __builtin_nontemporal_load(&rowp[i + 2]);
        long long q3 = __builtin_nontemporal_load(&rowp[i + 3]);
        unsigned p0 = xb[(size_t)(int)q0 * (D / 2) + t];
        unsigned p1 = xb[(size_t)(int)q1 * (D / 2) + t];
        unsigned p2 = xb[(size_t)(int)q2 * (D / 2) + t];
        unsigned p3 = xb[(size_t)(int)q3 * (D / 2) + t];
        float v0 = __int_as_float((int)(q0 >> 32));
        float v1 = __int_as_float((int)(q1 >> 32));
        float v2 = __int_as_float((int)(q2 >> 32));
        float v3 = __int_as_float((int)(q3 >> 32));
        a0 += v0 * __uint_as_float(p0 << 16);
        a1 += v0 * __uint_as_float(p0 & 0xffff0000u);
        a0 += v1 * __uint_as_float(p1 << 16);
        a1 += v1 * __uint_as_float(p1 & 0xffff0000u);
        a0 += v2 * __uint_as_float(p2 << 16);
        a1 += v2 * __uint_as_float(p2 & 0xffff0000u);
        a0 += v3 * __uint_as_float(p3 << 16);
        a1 += v3 * __uint_as_float(p3 & 0xffff0000u);
    }
    for (; i < deg; ++i) {
        long long q0 = __builtin_nontemporal_load(&rowp[i]);
        float v0 = __int_as_float((int)(q0 >> 32));
        unsigned p0 = xb[(size_t)(int)q0 * (D / 2) + t];
        a0 += v0 * __uint_as_float(p0 << 16);
        a1 += v0 * __uint_as_float(p0 & 0xffff0000u);
    }
    const int novf = min(g_novf, OVF_MAX);
    if (novf > 0) {                          // correctness fallback (empty)
        for (int j = 0; j < novf; ++j) {
            if (g_ovf_row[j] == r) {
                int2 e0 = g_ovf_edge[j];
                float v0 = __int_as_float(e0.y);
                unsigned p0 = xb[(size_t)e0.x * (D / 2) + t];
                a0 += v0 * __uint_as_float(p0 << 16);
                a1 += v0 * __uint_as_float(p0 & 0xffff0000u);
            }
        }
    }
    // no relu: out = relu(Y @ W) happens in the GEMM epilogue
    y[(size_t)r * (D / 2) + t] =
        (unsigned)f2bf(a0) | ((unsigned)f2bf(a1) << 16);
}

// --------------------------- out = relu(Y @ W), per-wave 16x64 tile, K=256
__launch_bounds__(256)
__global__ void gemm_kernel(const unsigned short* __restrict__ Yb,
                            float* __restrict__ out) {
    __shared__ float tile[4][16][68];
    const int g    = blockIdx.x;
    const int wave = threadIdx.x >> 6;
    const int lane = threadIdx.x & 63;
    const int m0   = g * 16;
    const int n0   = wave * 64;
    const int lm   = lane & 15;
    const int q    = lane >> 4;

    f32x4 acc0 = {}, acc1 = {}, acc2 = {}, acc3 = {};

    #pragma unroll
    for (int s = 0; s < 8; ++s) {
        bf16x8 av = *(const bf16x8*)&Yb[(size_t)(m0 + lm) * D + s * 32 + q * 8];
        const unsigned short* bp =
            &g_wtp[((size_t)(wave * 4) * 8 + s) * 512 + lane * 8];
        bf16x8 b0 = *(const bf16x8*)&bp[0 * 4096];
        bf16x8 b1 = *(const bf16x8*)&bp[1 * 4096];
        bf16x8 b2 = *(const bf16x8*)&bp[2 * 4096];
        bf16x8 b3 = *(const bf16x8*)&bp[3 * 4096];
        acc0 = __builtin_amdgcn_mfma_f32_16x16x32_bf16(av, b0, acc0, 0, 0, 0);
        acc1 = __builtin_amdgcn_mfma_f32_16x16x32_bf16(av, b1, acc1, 0, 0, 0);
        acc2 = __builtin_amdgcn_mfma_f32_16x16x32_bf16(av, b2, acc2, 0, 0, 0);
        acc3 = __builtin_amdgcn_mfma_f32_16x16x32_bf16(av, b3, acc3, 0, 0, 0);
    }

    #pragma unroll
    for (int r = 0; r < 4; ++r) {
        tile[wave][q * 4 + r][ 0 + lm] = acc0[r];
        tile[wave][q * 4 + r][16 + lm] = acc1[r];
        tile[wave][q * 4 + r][32 + lm] = acc2[r];
        tile[wave][q * 4 + r][48 + lm] = acc3[r];
    }
    const int row  = lane >> 2;
    const int cseg = (lane & 3) * 16;
    float ov[16];
    #pragma unroll
    for (int j = 0; j < 16; ++j)
        ov[j] = fmaxf(tile[wave][row][cseg + j], 0.f);
    float* dst = &out[(size_t)(m0 + row) * D + n0 + cseg];
    #pragma unroll
    for (int j = 0; j < 4; ++j)
        __builtin_nontemporal_store(*(const f32x4*)&ov[j * 4], (f32x4*)&dst[j * 4]);
}

// ---------------------------------------------------------------- launcher
#define XB_BYTES   ((size_t)N_NODES * D * 2)            // 51.2 MB
#define Y_BYTES    ((size_t)N_NODES * D * 2)            // 51.2 MB
#define BIN_BYTES  ((size_t)NB1 * CAPB1 * 8)            // 27.3 MB
#define GRP_BYTES  ((size_t)NQ * QCAP * 8)              // 28.9 MB
#define ROFS_BYTES ((size_t)NQ * QROWS * 8)             // 803 KB
#define ALIGNUP(v) (((v) + 255) & ~(size_t)255)

extern "C" void kernel_launch(void* const* d_in, const int* in_sizes, int n_in,
                              void* d_out, int out_size, void* d_ws, size_t ws_size,
                              hipStream_t stream) {
    const float* x        = (const float*)d_in[0];
    const float* weight   = (const float*)d_in[1];
    const float* edge_val = (const float*)d_in[2];
    const int*   edge_row = (const int*)d_in[3];
    const int*   edge_col = (const int*)d_in[4];
    float* out = (float*)d_out;

    static void* s_xb = nullptr; static void* s_y = nullptr;
    static void* s_bin = nullptr; static void* s_grp = nullptr;
    static void* s_rofs = nullptr; static void* s_b1cur = nullptr;
    static void* s_novf = nullptr;
    if (!s_xb) {
        hipGetSymbolAddress(&s_xb,    HIP_SYMBOL(g_xb_fb));
        hipGetSymbolAddress(&s_y,     HIP_SYMBOL(g_y_fb));
        hipGetSymbolAddress(&s_bin,   HIP_SYMBOL(g_binned_fb));
        hipGetSymbolAddress(&s_grp,   HIP_SYMBOL(g_grp_fb));
        hipGetSymbolAddress(&s_rofs,  HIP_SYMBOL(g_rofs_fb));
        hipGetSymbolAddress(&s_b1cur, HIP_SYMBOL(g_b1cur));
        hipGetSymbolAddress(&s_novf,  HIP_SYMBOL(g_novf));
    }
    unsigned short* xb;  unsigned* y;  int2* binned;  int2* grp;  int2* rofs;
    const size_t need = ALIGNUP(XB_BYTES) + ALIGNUP(Y_BYTES) +
                        ALIGNUP(BIN_BYTES) + ALIGNUP(GRP_BYTES) +
                        ALIGNUP(ROFS_BYTES);
    if (d_ws && ws_size >= need) {
        char* p = (char*)d_ws;
        xb     = (unsigned short*)p; p += ALIGNUP(XB_BYTES);
        y      = (unsigned*)p;       p += ALIGNUP(Y_BYTES);
        binned = (int2*)p;           p += ALIGNUP(BIN_BYTES);
        grp    = (int2*)p;           p += ALIGNUP(GRP_BYTES);
        rofs   = (int2*)p;
    } else {
        xb     = (unsigned short*)s_xb;
        y      = (unsigned*)s_y;
        binned = (int2*)s_bin;
        grp    = (int2*)s_grp;
        rofs   = (int2*)s_rofs;
    }

    hipMemsetAsync(s_b1cur, 0, (size_t)NB1 * 16 * 4, stream);
    hipMemsetAsync(s_novf, 0, 4, stream);
    binA_cast_pack_kernel<<<NBLK_A + CAST_BLOCKS + PACK_BLOCKS, 256, 0, stream>>>(
        x, weight, edge_val, edge_row, edge_col, binned, xb);
    binB_sort_kernel<<<NQ, 512, 0, stream>>>(binned, grp, rofs);
    spmm_kernel<<<SPMM_QTR, 128, 0, stream>>>(grp, rofs, xb, y, 0);
    spmm_kernel<<<SPMM_QTR, 128, 0, stream>>>(grp, rofs, xb, y, SPMM_QTR);
    spmm_kernel<<<SPMM_QTR, 128, 0, stream>>>(grp, rofs, xb, y, SPMM_QTR * 2);
    spmm_kernel<<<SPMM_QTR, 128, 0, stream>>>(grp, rofs, xb, y, SPMM_QTR * 3);
    gemm_kernel<<<GEMM_BLOCKS, 256, 0, stream>>>((const unsigned short*)y, out);
}

// Round 8
// 567.012 us; speedup vs baseline: 1.6405x; 1.0823x over previous
//
#include <hip/hip_runtime.h>

#define N_NODES 100000
#define N_EDGES 3200000
#define D 256
#define OVF_MAX 8192

#define NB1 98                      // coarse buckets (row >> 10)
#define CAPB1 34816                 // bucket capacity (mean 32653, +12 sigma)
#define CHUNK 3072                  // edges per binA block (24 KB LDS staging)
#define NBLK_A ((N_EDGES + CHUNK - 1) / CHUNK)   // 1042

#define NQ (NB1 * 4)                // binB blocks: (bucket, quarter) = 392
#define QROWS 256                   // rows per quarter
#define QCAP 9216                   // compact segment cap (mean 8192, +11 sigma)

#define CAST_BLOCKS 6250            // 25.6M elems / (256 thr * 16)
#define PACK_BLOCKS 64
#define GEMM_BLOCKS (N_NODES / 16)  // 6250
#define SPMM_HALF 50000             // rows per spmm launch

typedef __attribute__((ext_vector_type(8))) short bf16x8;
typedef __attribute__((ext_vector_type(4))) float f32x4;

// ---------------- small persistent scratch (always device globals) ----------
__device__ unsigned short g_wtp[(size_t)16 * 8 * 64 * 8];   // 128 KB packed W^T
// [k*16]: 64B-padded bucket cursors; [NB1*16]: novf  (single memset clears all)
__device__ int   g_ctr[NB1 * 16 + 16];
__device__ int   g_ovf_row[OVF_MAX];
__device__ int2  g_ovf_edge[OVF_MAX];
#define NOVF_IDX (NB1 * 16)

// ---------------- big scratch: d_ws if big enough, else these fallbacks -----
__device__ unsigned short g_xb_fb[(size_t)N_NODES * D];     // 51.2 MB
__device__ unsigned       g_y_fb[(size_t)N_NODES * (D / 2)];// 51.2 MB
__device__ int2           g_binned_fb[(size_t)NB1 * CAPB1]; // 27.3 MB
__device__ int2           g_grp_fb[(size_t)NQ * QCAP];      // 28.9 MB compact recs
__device__ int2           g_rofs_fb[(size_t)NQ * QROWS];    // 803 KB {ofs,cnt}/row

// fp32 -> bf16 round-to-nearest-even
__device__ __forceinline__ unsigned short f2bf(float f) {
    unsigned u = __float_as_uint(f);
    unsigned r = u + 0x7fffu + ((u >> 16) & 1u);
    return (unsigned short)(r >> 16);
}

// ------- fused: cast x fp32->bf16 || pack W^T — zero LDS, full occupancy
__launch_bounds__(256)
__global__ void cast_pack_kernel(const float* __restrict__ x,
                                 const float* __restrict__ W,
                                 unsigned short* __restrict__ xb) {
    const int tid = threadIdx.x;
    const int b = blockIdx.x;
    if (b < CAST_BLOCKS) {
        const size_t blockBase = (size_t)b * 4096;
        #pragma unroll
        for (int j = 0; j < 4; ++j) {
            size_t idx = blockBase + (size_t)(j * 256 + tid) * 4;
            float4 f = *(const float4*)&x[idx];
            unsigned short o[4];
            o[0] = f2bf(f.x); o[1] = f2bf(f.y);
            o[2] = f2bf(f.z); o[3] = f2bf(f.w);
            *(uint2*)&xb[idx] = *(const uint2*)o;
        }
    } else {
        // pack W^T MFMA-fragment-contiguous: p = ((nt*8+s)*64+lane)*8+i :
        // n = nt*16+(lane&15), k = s*32+(lane>>4)*8+i  -> source W[k][n]
        int pb = ((b - CAST_BLOCKS) * 256 + tid) * 4;
        #pragma unroll
        for (int j = 0; j < 4; ++j) {
            int p    = pb + j;
            int i8   = p & 7;
            int lane = (p >> 3) & 63;
            int s    = (p >> 9) & 7;
            int nt   = p >> 12;
            int n = nt * 16 + (lane & 15);
            int k = s * 32 + (lane >> 4) * 8 + i8;
            g_wtp[p] = f2bf(W[(size_t)k * D + n]);
        }
    }
}

// ---------------- binA-slim: coarse bin by row>>10, 28.6 KB LDS -> 5 blk/CU
// Split counters (threads <128 / >=128 use separate copies) halve LDS atomic
// conflicts in both count and place passes; flush runs ~250 B contiguous.
__launch_bounds__(256)
__global__ void binA_kernel(const float* __restrict__ edge_val,
                            const int* __restrict__ edge_row,
                            const int* __restrict__ edge_col,
                            int2* __restrict__ binned) {
    __shared__ int2 rec[CHUNK];              // 24 KB
    __shared__ unsigned char bid[CHUNK];     // 3 KB
    __shared__ int c2[2][NB1];               // split counters / cursors
    __shared__ int snap0[NB1];               // copy-0 count snapshot
    __shared__ int pre[NB1 + 1];
    __shared__ int bas[NB1];
    const int tid = threadIdx.x;
    const int half = tid >> 7;
    const int e0 = blockIdx.x * CHUNK;

    for (int k = tid; k < 2 * NB1; k += 256) ((int*)c2)[k] = 0;
    __syncthreads();
    // count pass (split copies)
    #pragma unroll
    for (int j = 0; j < CHUNK / 256; ++j) {
        int e = e0 + tid + j * 256;
        if (e < N_EDGES) atomicAdd(&c2[half][edge_row[e] >> 10], 1);
    }
    __syncthreads();
    if (tid == 0) {                          // serial scan over 98 (hidden @5blk/CU)
        int run = 0;
        for (int k = 0; k < NB1; ++k) {
            int c0 = c2[0][k];
            snap0[k] = c0;
            pre[k] = run;
            run += c0 + c2[1][k];
        }
        pre[NB1] = run;
    }
    __syncthreads();
    for (int k = tid; k < NB1; k += 256) {
        int tot = snap0[k] + c2[1][k];
        bas[k] = tot ? atomicAdd(&g_ctr[k * 16], tot) : 0;
    }
    __syncthreads();
    for (int k = tid; k < 2 * NB1; k += 256) ((int*)c2)[k] = 0;  // reuse: cursors
    __syncthreads();
    // place pass (split cursors: copy1 starts after copy0's share)
    #pragma unroll
    for (int j = 0; j < CHUNK / 256; ++j) {
        int e = e0 + tid + j * 256;
        if (e < N_EDGES) {
            int r = edge_row[e];
            int k = r >> 10;
            int o = atomicAdd(&c2[half][k], 1);
            int pos = pre[k] + (half ? snap0[k] : 0) + o;
            int2 pk;
            pk.x = edge_col[e] | ((r & 1023) << 17); // col:17b | row_local:10b
            pk.y = __float_as_int(edge_val[e]);
            rec[pos] = pk;
            bid[pos] = (unsigned char)k;
        }
    }
    __syncthreads();
    // flush: consecutive i -> consecutive dest within bucket (bursts)
    const int total = pre[NB1];
    for (int i = tid; i < total; i += 256) {
        int k = bid[i];
        int dest = bas[k] + (i - pre[k]);
        int2 pk = rec[i];
        if (dest < CAPB1) {
            binned[(size_t)k * CAPB1 + dest] = pk;
        } else {
            int o = atomicAdd(&g_ctr[NOVF_IDX], 1);
            if (o < OVF_MAX) {
                g_ovf_row[o] = (k << 10) | (pk.x >> 17);
                int2 ov; ov.x = pk.x & 0x1FFFF; ov.y = pk.y;
                g_ovf_edge[o] = ov;
            }
        }
    }
}

// ---------------- binB_sort v2: 1024 threads (full wave occupancy at 2 blk/CU)
// + Hillis-Steele scan (replaces O(n^2) brute force). (bucket, quarter) ->
// row-compact segment; the fine scatter never touches global memory.
__launch_bounds__(1024)
__global__ void binB_sort_kernel(const int2* __restrict__ binned,
                                 int2* __restrict__ grp,
                                 int2* __restrict__ rofs) {
    __shared__ int2 srec[QCAP];              // 73.7 KB
    __shared__ int cnt[QROWS];
    __shared__ int scn[QROWS];
    __shared__ int ofs[QROWS];
    __shared__ int cur[QROWS];
    const int tid = threadIdx.x;
    const int b   = blockIdx.x >> 2;         // bucket
    const int qtr = blockIdx.x & 3;          // quarter (256 rows)

    const int n = min(g_ctr[b * 16], CAPB1);
    const int2* src = &binned[(size_t)b * CAPB1];

    if (tid < QROWS) { cnt[tid] = 0; cur[tid] = 0; }
    __syncthreads();
    // pass 1: count this quarter's rows
    for (int i = tid; i < n; i += 1024) {
        int rl = src[i].x >> 17;
        if ((rl >> 8) == qtr) atomicAdd(&cnt[rl & 255], 1);
    }
    __syncthreads();
    // Hillis-Steele inclusive scan over 256 counts
    if (tid < QROWS) scn[tid] = cnt[tid];
    __syncthreads();
    #pragma unroll
    for (int d = 1; d < QROWS; d <<= 1) {
        int v = 0;
        if (tid < QROWS) { v = scn[tid]; if (tid >= d) v += scn[tid - d]; }
        __syncthreads();
        if (tid < QROWS) scn[tid] = v;
        __syncthreads();
    }
    if (tid < QROWS) ofs[tid] = scn[tid] - cnt[tid];   // exclusive
    __syncthreads();
    // pass 2: place compactly (L2/L3-hot re-read)
    for (int i = tid; i < n; i += 1024) {
        int2 pk = src[i];
        int rl = pk.x >> 17;
        if ((rl >> 8) == qtr) {
            int r8 = rl & 255;
            int p = ofs[r8] + atomicAdd(&cur[r8], 1);
            int2 o2; o2.x = pk.x & 0x1FFFF; o2.y = pk.y;
            if (p < QCAP) {
                srec[p] = o2;
            } else {
                int o = atomicAdd(&g_ctr[NOVF_IDX], 1);
                if (o < OVF_MAX) {
                    g_ovf_row[o] = (b << 10) + (qtr << 8) + r8;
                    g_ovf_edge[o] = o2;
                }
            }
        }
    }
    __syncthreads();
    // flush: contiguous, line-aligned (blk base = blk * 73728 B)
    const int total = min(scn[QROWS - 1], QCAP);
    int2* dst = &grp[(size_t)blockIdx.x * QCAP];
    for (int i = tid; i < total; i += 1024) dst[i] = srec[i];
    if (tid < QROWS) {
        int s = min(ofs[tid], QCAP);
        int e = min(ofs[tid] + cnt[tid], QCAP);
        int2 oc; oc.x = s; oc.y = e - s;
        rofs[(size_t)blockIdx.x * QROWS + tid] = oc;
    }
}

// ---------------------------------------------------------------- SpMM
// Y = A * x_bf16, bf16 out. One 128-thread block per row (proven: ~86% occ,
// ~3.9 TB/s); thread t owns features 2t, 2t+1. Two half launches keep the
// profiler cutoff at ~110 us.
__launch_bounds__(128)
__global__ void spmm_kernel(const int2* __restrict__ grp,
                            const int2* __restrict__ rofs,
                            const unsigned short* __restrict__ xbp,
                            unsigned* __restrict__ y,
                            int rowBase) {
    const int r = rowBase + blockIdx.x;
    const int t = threadIdx.x;
    const int blk = r >> 8;                  // (bucket, quarter) segment id
    const int2 oc = rofs[(size_t)blk * QROWS + (r & 255)];
    const int deg = oc.y;
    const long long* rowp =
        (const long long*)&grp[(size_t)blk * QCAP + oc.x];
    const unsigned* xb = (const unsigned*)xbp;

    float a0 = 0.f, a1 = 0.f;
    int i = 0;
    for (; i + 3 < deg; i += 4) {
        long long q0 = __builtin_nontemporal_load(&rowp[i]);
        long long q1 = __builtin_nontemporal_load(&rowp[i + 1]);
        long long q2 = __builtin_nontemporal_load(&rowp[i + 2]);
        long long q3 = __builtin_nontemporal_load(&rowp[i + 3]);
        unsigned p0 = xb[(size_t)(int)q0 * (D / 2) + t];
        unsigned p1 = xb[(size_t)(int)q1 * (D / 2) + t];
        unsigned p2 = xb[(size_t)(int)q2 * (D / 2) + t];
        unsigned p3 = xb[(size_t)(int)q3 * (D / 2) + t];
        float v0 = __int_as_float((int)(q0 >> 32));
        float v1 = __int_as_float((int)(q1 >> 32));
        float v2 = __int_as_float((int)(q2 >> 32));
        float v3 = __int_as_float((int)(q3 >> 32));
        a0 += v0 * __uint_as_float(p0 << 16);
        a1 += v0 * __uint_as_float(p0 & 0xffff0000u);
        a0 += v1 * __uint_as_float(p1 << 16);
        a1 += v1 * __uint_as_float(p1 & 0xffff0000u);
        a0 += v2 * __uint_as_float(p2 << 16);
        a1 += v2 * __uint_as_float(p2 & 0xffff0000u);
        a0 += v3 * __uint_as_float(p3 << 16);
        a1 += v3 * __uint_as_float(p3 & 0xffff0000u);
    }
    for (; i < deg; ++i) {
        long long q0 = __builtin_nontemporal_load(&rowp[i]);
        float v0 = __int_as_float((int)(q0 >> 32));
        unsigned p0 = xb[(size_t)(int)q0 * (D / 2) + t];
        a0 += v0 * __uint_as_float(p0 << 16);
        a1 += v0 * __uint_as_float(p0 & 0xffff0000u);
    }
    const int novf = min(g_ctr[NOVF_IDX], OVF_MAX);
    if (novf > 0) {                          // correctness fallback (empty)
        for (int j = 0; j < novf; ++j) {
            if (g_ovf_row[j] == r) {
                int2 e0 = g_ovf_edge[j];
                float v0 = __int_as_float(e0.y);
                unsigned p0 = xb[(size_t)e0.x * (D / 2) + t];
                a0 += v0 * __uint_as_float(p0 << 16);
                a1 += v0 * __uint_as_float(p0 & 0xffff0000u);
            }
        }
    }
    // no relu: out = relu(Y @ W) happens in the GEMM epilogue
    y[(size_t)r * (D / 2) + t] =
        (unsigned)f2bf(a0) | ((unsigned)f2bf(a1) << 16);
}

// --------------------------- out = relu(Y @ W), per-wave 16x64 tile, K=256
__launch_bounds__(256)
__global__ void gemm_kernel(const unsigned short* __restrict__ Yb,
                            float* __restrict__ out) {
    __shared__ float tile[4][16][68];
    const int g    = blockIdx.x;
    const int wave = threadIdx.x >> 6;
    const int lane = threadIdx.x & 63;
    const int m0   = g * 16;
    const int n0   = wave * 64;
    const int lm   = lane & 15;
    const int q    = lane >> 4;

    f32x4 acc0 = {}, acc1 = {}, acc2 = {}, acc3 = {};

    #pragma unroll
    for (int s = 0; s < 8; ++s) {
        bf16x8 av = *(const bf16x8*)&Yb[(size_t)(m0 + lm) * D + s * 32 + q * 8];
        const unsigned short* bp =
            &g_wtp[((size_t)(wave * 4) * 8 + s) * 512 + lane * 8];
        bf16x8 b0 = *(const bf16x8*)&bp[0 * 4096];
        bf16x8 b1 = *(const bf16x8*)&bp[1 * 4096];
        bf16x8 b2 = *(const bf16x8*)&bp[2 * 4096];
        bf16x8 b3 = *(const bf16x8*)&bp[3 * 4096];
        acc0 = __builtin_amdgcn_mfma_f32_16x16x32_bf16(av, b0, acc0, 0, 0, 0);
        acc1 = __builtin_amdgcn_mfma_f32_16x16x32_bf16(av, b1, acc1, 0, 0, 0);
        acc2 = __builtin_amdgcn_mfma_f32_16x16x32_bf16(av, b2, acc2, 0, 0, 0);
        acc3 = __builtin_amdgcn_mfma_f32_16x16x32_bf16(av, b3, acc3, 0, 0, 0);
    }

    #pragma unroll
    for (int r = 0; r < 4; ++r) {
        tile[wave][q * 4 + r][ 0 + lm] = acc0[r];
        tile[wave][q * 4 + r][16 + lm] = acc1[r];
        tile[wave][q * 4 + r][32 + lm] = acc2[r];
        tile[wave][q * 4 + r][48 + lm] = acc3[r];
    }
    const int row  = lane >> 2;
    const int cseg = (lane & 3) * 16;
    float ov[16];
    #pragma unroll
    for (int j = 0; j < 16; ++j)
        ov[j] = fmaxf(tile[wave][row][cseg + j], 0.f);
    float* dst = &out[(size_t)(m0 + row) * D + n0 + cseg];
    #pragma unroll
    for (int j = 0; j < 4; ++j)
        __builtin_nontemporal_store(*(const f32x4*)&ov[j * 4], (f32x4*)&dst[j * 4]);
}

// ---------------------------------------------------------------- launcher
#define XB_BYTES   ((size_t)N_NODES * D * 2)            // 51.2 MB
#define Y_BYTES    ((size_t)N_NODES * D * 2)            // 51.2 MB
#define BIN_BYTES  ((size_t)NB1 * CAPB1 * 8)            // 27.3 MB
#define GRP_BYTES  ((size_t)NQ * QCAP * 8)              // 28.9 MB
#define ROFS_BYTES ((size_t)NQ * QROWS * 8)             // 803 KB
#define ALIGNUP(v) (((v) + 255) & ~(size_t)255)

extern "C" void kernel_launch(void* const* d_in, const int* in_sizes, int n_in,
                              void* d_out, int out_size, void* d_ws, size_t ws_size,
                              hipStream_t stream) {
    const float* x        = (const float*)d_in[0];
    const float* weight   = (const float*)d_in[1];
    const float* edge_val = (const float*)d_in[2];
    const int*   edge_row = (const int*)d_in[3];
    const int*   edge_col = (const int*)d_in[4];
    float* out = (float*)d_out;

    static void* s_xb = nullptr; static void* s_y = nullptr;
    static void* s_bin = nullptr; static void* s_grp = nullptr;
    static void* s_rofs = nullptr; static void* s_ctr = nullptr;
    if (!s_xb) {
        hipGetSymbolAddress(&s_xb,   HIP_SYMBOL(g_xb_fb));
        hipGetSymbolAddress(&s_y,    HIP_SYMBOL(g_y_fb));
        hipGetSymbolAddress(&s_bin,  HIP_SYMBOL(g_binned_fb));
        hipGetSymbolAddress(&s_grp,  HIP_SYMBOL(g_grp_fb));
        hipGetSymbolAddress(&s_rofs, HIP_SYMBOL(g_rofs_fb));
        hipGetSymbolAddress(&s_ctr,  HIP_SYMBOL(g_ctr));
    }
    unsigned short* xb;  unsigned* y;  int2* binned;  int2* grp;  int2* rofs;
    const size_t need = ALIGNUP(XB_BYTES) + ALIGNUP(Y_BYTES) +
                        ALIGNUP(BIN_BYTES) + ALIGNUP(GRP_BYTES) +
                        ALIGNUP(ROFS_BYTES);
    if (d_ws && ws_size >= need) {
        char* p = (char*)d_ws;
        xb     = (unsigned short*)p; p += ALIGNUP(XB_BYTES);
        y      = (unsigned*)p;       p += ALIGNUP(Y_BYTES);
        binned = (int2*)p;           p += ALIGNUP(BIN_BYTES);
        grp    = (int2*)p;           p += ALIGNUP(GRP_BYTES);
        rofs   = (int2*)p;
    } else {
        xb     = (unsigned short*)s_xb;
        y      = (unsigned*)s_y;
        binned = (int2*)s_bin;
        grp    = (int2*)s_grp;
        rofs   = (int2*)s_rofs;
    }

    hipMemsetAsync(s_ctr, 0, (size_t)(NB1 * 16 + 16) * 4, stream);
    cast_pack_kernel<<<CAST_BLOCKS + PACK_BLOCKS, 256, 0, stream>>>(x, weight, xb);
    binA_kernel<<<NBLK_A, 256, 0, stream>>>(edge_val, edge_row, edge_col, binned);
    binB_sort_kernel<<<NQ, 1024, 0, stream>>>(binned, grp, rofs);
    spmm_kernel<<<SPMM_HALF, 128, 0, stream>>>(grp, rofs, xb, y, 0);
    spmm_kernel<<<SPMM_HALF, 128, 0, stream>>>(grp, rofs, xb, y, SPMM_HALF);
    gemm_kernel<<<GEMM_BLOCKS, 256, 0, stream>>>((const unsigned short*)y, out);
}